// Round 7
// baseline (331.035 us; speedup 1.0000x reference)
//
#include <hip/hip_runtime.h>
#include <hip/hip_bf16.h>

typedef __bf16 bf16_t;
typedef __attribute__((ext_vector_type(8))) __bf16 bfrag;   // 8 bf16 = 4 VGPRs (MFMA A/B frag)
typedef __attribute__((ext_vector_type(4))) __bf16 bf16x4;  // 8B packed store
typedef __attribute__((ext_vector_type(4))) float f32x4;    // MFMA C/D frag

#define SEQ    4096
#define NDIM   1024
#define NHEAD  16
#define HD     64
#define NBATCH 2
#define MROWS  (NBATCH * SEQ)   // 8192
#define LQK    2048             // fused Q|K row stride
#define PSTR   76               // Pw key-stride (bank-friendly)

// async 16B global -> LDS (m97 pattern). l must be wave-uniform; lane i lands at l + i*16.
__device__ __forceinline__ void gload_lds16(const bf16_t* g, bf16_t* l) {
    __builtin_amdgcn_global_load_lds(
        (const __attribute__((address_space(1))) unsigned int*)g,
        (__attribute__((address_space(3))) unsigned int*)l,
        16, 0, 0);
}

// ---------------------------------------------------------------------------
// GEMM: C[M,N] = A[M,K] @ W[N,K]^T + bias   (bf16 in, f32 acc, OT out)
// m97 structure: 128x128 tile, BK=32, global_load_lds width-16 staging.
// Column blocks with col0 >= 2048 are written TRANSPOSED into Vt[b][h][d][s]
// (V-section of the fused QKV projection) instead of to C.
// ---------------------------------------------------------------------------
template <typename OT>
__global__ __launch_bounds__(256, 2)
void gemm_bt(const bf16_t* __restrict__ A, int lda,
             const bf16_t* __restrict__ W,
             const float* __restrict__ b0p, const float* __restrict__ b1p,
             const float* __restrict__ b2p,
             OT* __restrict__ C, int ldc, int K,
             bf16_t* __restrict__ VtOut)
{
    __shared__ __align__(16) bf16_t As[128 * 32];
    __shared__ __align__(16) bf16_t Bs[128 * 32];

    const int tid  = threadIdx.x;
    const int lane = tid & 63;
    const int wid  = tid >> 6;
    const int n16  = lane & 15;
    const int quad = lane >> 4;
    const int row0 = blockIdx.y * 128;
    const int col0 = blockIdx.x * 128;
    const int wrow = (wid >> 1) * 64;
    const int wcol = (wid & 1) * 64;
    const float* bias = (col0 < 1024) ? b0p : (col0 < 2048 ? b1p : b2p);
    const int bcol0 = col0 & 1023;

    f32x4 acc[4][4];
#pragma unroll
    for (int i = 0; i < 4; i++)
#pragma unroll
        for (int j = 0; j < 4; j++) acc[i][j] = (f32x4){0.f, 0.f, 0.f, 0.f};

    for (int k0 = 0; k0 < K; k0 += 32) {
#pragma unroll
        for (int it = 0; it < 2; it++) {
            int idx = tid + it * 256;          // 16B-chunk index 0..511
            int r   = idx >> 2;
            int c   = (idx & 3) * 8;
            gload_lds16(A + (size_t)(row0 + r) * lda + k0 + c, &As[(it * 256 + wid * 64) * 8]);
            gload_lds16(W + (size_t)(col0 + r) * K   + k0 + c, &Bs[(it * 256 + wid * 64) * 8]);
        }
        __syncthreads();

        bfrag af[4], bfg[4];
#pragma unroll
        for (int i = 0; i < 4; i++)
            af[i] = *(const bfrag*)(&As[(wrow + i * 16 + n16) * 32 + quad * 8]);
#pragma unroll
        for (int j = 0; j < 4; j++)
            bfg[j] = *(const bfrag*)(&Bs[(wcol + j * 16 + n16) * 32 + quad * 8]);

#pragma unroll
        for (int i = 0; i < 4; i++)
#pragma unroll
            for (int j = 0; j < 4; j++)
                acc[i][j] = __builtin_amdgcn_mfma_f32_16x16x32_bf16(af[i], bfg[j], acc[i][j], 0, 0, 0);
        __syncthreads();
    }

    if (col0 < 2048 || VtOut == nullptr) {
#pragma unroll
        for (int i = 0; i < 4; i++)
#pragma unroll
            for (int j = 0; j < 4; j++)
#pragma unroll
                for (int r = 0; r < 4; r++) {
                    int row = row0 + wrow + i * 16 + quad * 4 + r;
                    int col = wcol + j * 16 + n16;
                    float v = acc[i][j][r] + bias[bcol0 + col];
                    C[(size_t)row * ldc + col0 + col] = (OT)v;
                }
    } else {
        // V block: write transposed into Vt[(b*16+h)*64+d][s], packed 4 tokens
#pragma unroll
        for (int i = 0; i < 4; i++) {
#pragma unroll
            for (int j = 0; j < 4; j++) {
                int dg     = col0 + wcol + j * 16 + n16 - 2048;   // 0..1023
                int token0 = row0 + wrow + i * 16 + quad * 4;
                int bb     = token0 >> 12;
                float bv   = bias[bcol0 + wcol + j * 16 + n16];
                size_t vrow = ((size_t)bb * NHEAD + (dg >> 6)) * HD + (dg & 63);
                bf16x4 pk;
#pragma unroll
                for (int r = 0; r < 4; r++) pk[r] = (__bf16)(acc[i][j][r] + bv);
                *(bf16x4*)&VtOut[vrow * SEQ + (token0 & (SEQ - 1))] = pk;
            }
        }
    }
}

// ---------------------------------------------------------------------------
// fp32 -> bf16 casts
// ---------------------------------------------------------------------------
__global__ __launch_bounds__(256)
void cast_x(const float* __restrict__ s, bf16_t* __restrict__ d)
{
    size_t i = ((size_t)blockIdx.x * 256 + threadIdx.x) * 8;
    float4 a = *(const float4*)(s + i);
    float4 b = *(const float4*)(s + i + 4);
    bfrag o;
    o[0] = (__bf16)a.x; o[1] = (__bf16)a.y; o[2] = (__bf16)a.z; o[3] = (__bf16)a.w;
    o[4] = (__bf16)b.x; o[5] = (__bf16)b.y; o[6] = (__bf16)b.z; o[7] = (__bf16)b.w;
    *(bfrag*)(d + i) = o;
}

__global__ __launch_bounds__(256)
void cast_w(const float* __restrict__ wq, const float* __restrict__ wk,
            const float* __restrict__ wv, const float* __restrict__ wo,
            bf16_t* __restrict__ d)   // d = [Wq|Wk|Wv|Wo] bf16
{
    size_t t   = (size_t)blockIdx.x * 256 + threadIdx.x;   // 0..524287
    int    sel = (int)(t >> 17);
    const float* s = sel == 0 ? wq : (sel == 1 ? wk : (sel == 2 ? wv : wo));
    size_t off = (t & 131071) * 8;
    float4 a = *(const float4*)(s + off);
    float4 b = *(const float4*)(s + off + 4);
    bfrag o;
    o[0] = (__bf16)a.x; o[1] = (__bf16)a.y; o[2] = (__bf16)a.z; o[3] = (__bf16)a.w;
    o[4] = (__bf16)b.x; o[5] = (__bf16)b.y; o[6] = (__bf16)b.z; o[7] = (__bf16)b.w;
    *(bfrag*)(d + (size_t)sel * 1048576 + off) = o;
}

// ---------------------------------------------------------------------------
// Flash sliding-window attention, fully transposed frame (S^T / O^T).
// Block = (b,h, 64-query tile), 4 waves x 16 queries; lane owns ONE query
// (query = lane&15). No __syncthreads anywhere; LDS = wave-private Pw only.
//   S^T = K Q^T  : A = K frags (direct global), B = Q frags. C: col=query.
//   softmax      : per-lane scalar state; in-lane reduce + xor16/xor32 shfl.
//   P^T -> Pw    : 4 packed ds_write_b64 per iter ([query][key], stride 76).
//   O^T = V^T P^T: A = V^T frags (direct global Vt), B = P^T from Pw.
// ---------------------------------------------------------------------------
__global__ __launch_bounds__(256, 4)
void attn_win(const bf16_t* __restrict__ QK, const bf16_t* __restrict__ Vt,
              bf16_t* __restrict__ AO)
{
    __shared__ __align__(16) bf16_t Pw[4][16 * PSTR];   // 9728 B, wave-private

    const int tid  = threadIdx.x;
    const int wid  = tid >> 6;
    const int lane = tid & 63;
    const int n16  = lane & 15;
    const int quad = lane >> 4;

    const int q0 = blockIdx.x * 64;
    const int bh = blockIdx.y;
    const int b  = bh >> 4, h = bh & 15;
    const size_t bS   = (size_t)b * SEQ;
    const size_t hoff = (size_t)h * HD;
    const bf16_t* Vb  = Vt + (size_t)bh * HD * SEQ;   // [d][s]
    const int wstart  = q0 - 512;
    const int it0     = (q0 < 512) ? ((512 - q0) >> 6) : 0;

    // ---- Q B-frags (once): col n16 = query, k = dims ----
    const int qa = q0 + wid * 16 + n16;               // this lane's query
    bfrag bq0 = *(const bfrag*)(&QK[(bS + qa) * LQK + hoff + quad * 8]);
    bfrag bq1 = *(const bfrag*)(&QK[(bS + qa) * LQK + hoff + 32 + quad * 8]);

    f32x4 ao[4];                                       // O^T: d = j*16+quad*4+r
#pragma unroll
    for (int j = 0; j < 4; j++) ao[j] = (f32x4){0.f, 0.f, 0.f, 0.f};
    float m = -1e30f, l = 0.f;

    for (int it = it0; it < 9; ++it) {
        const int k0 = wstart + it * 64;

        // ---- S^T = K Q^T : 4 key-tiles ----
        f32x4 a[4];
#pragma unroll
        for (int nt = 0; nt < 4; nt++) {
            const bf16_t* krow = &QK[(bS + k0 + nt * 16 + n16) * LQK + 1024 + hoff];
            bfrag ak0 = *(const bfrag*)(krow + quad * 8);
            bfrag ak1 = *(const bfrag*)(krow + 32 + quad * 8);
            f32x4 s4 = (f32x4){0.f, 0.f, 0.f, 0.f};
            s4 = __builtin_amdgcn_mfma_f32_16x16x32_bf16(ak0, bq0, s4, 0, 0, 0);
            s4 = __builtin_amdgcn_mfma_f32_16x16x32_bf16(ak1, bq1, s4, 0, 0, 0);
            a[nt] = s4;
        }

        const bool msk = (it == 0) || (it == 8);
        if (msk) {
#pragma unroll
            for (int nt = 0; nt < 4; nt++)
#pragma unroll
                for (int r = 0; r < 4; r++) {
                    int ka = k0 + nt * 16 + quad * 4 + r;
                    bool valid = (ka >= qa - 511) & (ka <= qa);
                    a[nt][r] = valid ? a[nt][r] * 0.125f : -1e30f;
                }
        } else {
#pragma unroll
            for (int nt = 0; nt < 4; nt++)
#pragma unroll
                for (int r = 0; r < 4; r++) a[nt][r] *= 0.125f;
        }

        // ---- online softmax: per-lane scalar state ----
        float cm = -1e30f;
#pragma unroll
        for (int nt = 0; nt < 4; nt++)
#pragma unroll
            for (int r = 0; r < 4; r++) cm = fmaxf(cm, a[nt][r]);
        cm = fmaxf(cm, __shfl_xor(cm, 16, 64));
        cm = fmaxf(cm, __shfl_xor(cm, 32, 64));
        float mn    = fmaxf(m, cm);
        float alpha = __expf(m - mn);
        m = mn;
#pragma unroll
        for (int j = 0; j < 4; j++)
#pragma unroll
            for (int r = 0; r < 4; r++) ao[j][r] *= alpha;

        // ---- p = exp(s-m); packed b64 writes into Pw [query][key] ----
        float lacc = 0.f;
#pragma unroll
        for (int nt = 0; nt < 4; nt++) {
            bf16x4 pk;
#pragma unroll
            for (int r = 0; r < 4; r++) {
                float p = __expf(a[nt][r] - m);
                if (msk && a[nt][r] <= -1e29f) p = 0.f;
                lacc += p;
                pk[r] = (__bf16)p;
            }
            *(bf16x4*)&Pw[wid][n16 * PSTR + nt * 16 + quad * 4] = pk;
        }
        l = l * alpha + lacc;              // cross-quad l-reduce deferred to epilogue

        // ---- O^T += V^T P^T : 2 k-steps of 32 keys ----
#pragma unroll
        for (int ks = 0; ks < 2; ks++) {
            bfrag bp = *(const bfrag*)(&Pw[wid][n16 * PSTR + ks * 32 + quad * 8]);
#pragma unroll
            for (int j = 0; j < 4; j++) {
                bfrag av = *(const bfrag*)(&Vb[(size_t)(j * 16 + n16) * SEQ
                                               + k0 + ks * 32 + quad * 8]);
                ao[j] = __builtin_amdgcn_mfma_f32_16x16x32_bf16(av, bp, ao[j], 0, 0, 0);
            }
        }
    }

    // ---- epilogue: reduce l across quads, store O rows (packed b64) ----
    l += __shfl_xor(l, 16, 64);
    l += __shfl_xor(l, 32, 64);
    const float inv = 1.0f / l;
#pragma unroll
    for (int j = 0; j < 4; j++) {
        bf16x4 pk;
#pragma unroll
        for (int r = 0; r < 4; r++) pk[r] = (__bf16)(ao[j][r] * inv);
        *(bf16x4*)&AO[(bS + qa) * NDIM + hoff + j * 16 + quad * 4] = pk;
    }
}

// ---------------------------------------------------------------------------
extern "C" void kernel_launch(void* const* d_in, const int* in_sizes, int n_in,
                              void* d_out, int out_size, void* d_ws, size_t ws_size,
                              hipStream_t stream)
{
    const float* x  = (const float*)d_in[0];
    const float* Wq = (const float*)d_in[1];
    const float* bq = (const float*)d_in[2];
    const float* Wk = (const float*)d_in[3];
    const float* bk = (const float*)d_in[4];
    const float* Wv = (const float*)d_in[5];
    const float* bv = (const float*)d_in[6];
    const float* Wo = (const float*)d_in[7];
    const float* bo = (const float*)d_in[8];
    float* out = (float*)d_out;

    // ws: QKb [8192][2048] bf16 (32 MiB) | AbX [8192][1024] bf16 (16 MiB)
    //     Wc [Wq|Wk|Wv|Wo] bf16 (8 MiB)
    const size_t QK_E = (size_t)MROWS * LQK;
    const size_t X_E  = (size_t)MROWS * NDIM;
    if (ws_size < (QK_E + X_E + 4u * 1048576u) * sizeof(bf16_t)) return;

    bf16_t* QKb = (bf16_t*)d_ws;
    bf16_t* AbX = QKb + QK_E;
    bf16_t* Wc  = AbX + X_E;
    bf16_t* Wob = Wc + 3u * 1048576u;
    bf16_t* Vtg = (bf16_t*)d_out;   // 16.8 MB scratch inside the 33.5 MB out buf;
                                    // dead before the O-proj overwrites d_out.

    dim3 blk(256);

    cast_x<<<dim3(4096), blk, 0, stream>>>(x, AbX);
    cast_w<<<dim3(2048), blk, 0, stream>>>(Wq, Wk, Wv, Wo, Wc);

    // fused QKV projection: Q,K -> QKb (stride 2048); V -> Vtg transposed
    gemm_bt<bf16_t><<<dim3(3072 / 128, MROWS / 128), blk, 0, stream>>>(
        AbX, NDIM, Wc, bq, bk, bv, QKb, LQK, NDIM, Vtg);

    attn_win<<<dim3(SEQ / 64, NBATCH * NHEAD), blk, 0, stream>>>(QKb, Vtg, AbX);

    // output projection: [8192,1024] x [1024,1024]^T -> fp32 out
    gemm_bt<float><<<dim3(NDIM / 128, MROWS / 128), blk, 0, stream>>>(
        AbX, NDIM, Wob, bo, bo, bo, out, NDIM, NDIM, nullptr);
}

// Round 8
// 279.329 us; speedup vs baseline: 1.1851x; 1.1851x over previous
//
#include <hip/hip_runtime.h>
#include <hip/hip_bf16.h>

typedef __bf16 bf16_t;
typedef __attribute__((ext_vector_type(8))) __bf16 bfrag;   // 8 bf16 = 4 VGPRs (MFMA A/B frag)
typedef __attribute__((ext_vector_type(4))) __bf16 bf16x4;  // 8B packed store
typedef __attribute__((ext_vector_type(4))) float f32x4;    // MFMA C/D frag

#define SEQ    4096
#define NDIM   1024
#define NHEAD  16
#define HD     64
#define NBATCH 2
#define MROWS  (NBATCH * SEQ)   // 8192
#define LQK    2048             // fused Q|K row stride
#define PSTR   76               // Pw key-stride (bank-friendly, 0 conflicts in R7)

// async 16B global -> LDS (m97 pattern). l must be wave-uniform; lane i lands at l + i*16.
__device__ __forceinline__ void gload_lds16(const bf16_t* g, bf16_t* l) {
    __builtin_amdgcn_global_load_lds(
        (const __attribute__((address_space(1))) unsigned int*)g,
        (__attribute__((address_space(3))) unsigned int*)l,
        16, 0, 0);
}

// ---------------------------------------------------------------------------
// GEMM: C[M,N] = A[M,K] @ W[N,K]^T + bias   (bf16 in, f32 acc, OT out)
// m97 structure: 128x128 tile, BK=32, global_load_lds width-16 staging.
// Column blocks with col0 >= 2048 are written TRANSPOSED into Vt[b][h][d][s].
// ---------------------------------------------------------------------------
template <typename OT>
__global__ __launch_bounds__(256, 2)
void gemm_bt(const bf16_t* __restrict__ A, int lda,
             const bf16_t* __restrict__ W,
             const float* __restrict__ b0p, const float* __restrict__ b1p,
             const float* __restrict__ b2p,
             OT* __restrict__ C, int ldc, int K,
             bf16_t* __restrict__ VtOut)
{
    __shared__ __align__(16) bf16_t As[128 * 32];
    __shared__ __align__(16) bf16_t Bs[128 * 32];

    const int tid  = threadIdx.x;
    const int lane = tid & 63;
    const int wid  = tid >> 6;
    const int n16  = lane & 15;
    const int quad = lane >> 4;
    const int row0 = blockIdx.y * 128;
    const int col0 = blockIdx.x * 128;
    const int wrow = (wid >> 1) * 64;
    const int wcol = (wid & 1) * 64;
    const float* bias = (col0 < 1024) ? b0p : (col0 < 2048 ? b1p : b2p);
    const int bcol0 = col0 & 1023;

    f32x4 acc[4][4];
#pragma unroll
    for (int i = 0; i < 4; i++)
#pragma unroll
        for (int j = 0; j < 4; j++) acc[i][j] = (f32x4){0.f, 0.f, 0.f, 0.f};

    for (int k0 = 0; k0 < K; k0 += 32) {
#pragma unroll
        for (int it = 0; it < 2; it++) {
            int idx = tid + it * 256;          // 16B-chunk index 0..511
            int r   = idx >> 2;
            int c   = (idx & 3) * 8;
            gload_lds16(A + (size_t)(row0 + r) * lda + k0 + c, &As[(it * 256 + wid * 64) * 8]);
            gload_lds16(W + (size_t)(col0 + r) * K   + k0 + c, &Bs[(it * 256 + wid * 64) * 8]);
        }
        __syncthreads();

        bfrag af[4], bfg[4];
#pragma unroll
        for (int i = 0; i < 4; i++)
            af[i] = *(const bfrag*)(&As[(wrow + i * 16 + n16) * 32 + quad * 8]);
#pragma unroll
        for (int j = 0; j < 4; j++)
            bfg[j] = *(const bfrag*)(&Bs[(wcol + j * 16 + n16) * 32 + quad * 8]);

#pragma unroll
        for (int i = 0; i < 4; i++)
#pragma unroll
            for (int j = 0; j < 4; j++)
                acc[i][j] = __builtin_amdgcn_mfma_f32_16x16x32_bf16(af[i], bfg[j], acc[i][j], 0, 0, 0);
        __syncthreads();
    }

    if (col0 < 2048 || VtOut == nullptr) {
#pragma unroll
        for (int i = 0; i < 4; i++)
#pragma unroll
            for (int j = 0; j < 4; j++)
#pragma unroll
                for (int r = 0; r < 4; r++) {
                    int row = row0 + wrow + i * 16 + quad * 4 + r;
                    int col = wcol + j * 16 + n16;
                    float v = acc[i][j][r] + bias[bcol0 + col];
                    C[(size_t)row * ldc + col0 + col] = (OT)v;
                }
    } else {
        // V block: write transposed into Vt[(b*16+h)*64+d][s], packed 4 tokens
#pragma unroll
        for (int i = 0; i < 4; i++) {
#pragma unroll
            for (int j = 0; j < 4; j++) {
                int dg     = col0 + wcol + j * 16 + n16 - 2048;   // 0..1023
                int token0 = row0 + wrow + i * 16 + quad * 4;
                int bb     = token0 >> 12;
                float bv   = bias[bcol0 + wcol + j * 16 + n16];
                size_t vrow = ((size_t)bb * NHEAD + (dg >> 6)) * HD + (dg & 63);
                bf16x4 pk;
#pragma unroll
                for (int r = 0; r < 4; r++) pk[r] = (__bf16)(acc[i][j][r] + bv);
                *(bf16x4*)&VtOut[vrow * SEQ + (token0 & (SEQ - 1))] = pk;
            }
        }
    }
}

// ---------------------------------------------------------------------------
// fp32 -> bf16 casts
// ---------------------------------------------------------------------------
__global__ __launch_bounds__(256)
void cast_x(const float* __restrict__ s, bf16_t* __restrict__ d)
{
    size_t i = ((size_t)blockIdx.x * 256 + threadIdx.x) * 8;
    float4 a = *(const float4*)(s + i);
    float4 b = *(const float4*)(s + i + 4);
    bfrag o;
    o[0] = (__bf16)a.x; o[1] = (__bf16)a.y; o[2] = (__bf16)a.z; o[3] = (__bf16)a.w;
    o[4] = (__bf16)b.x; o[5] = (__bf16)b.y; o[6] = (__bf16)b.z; o[7] = (__bf16)b.w;
    *(bfrag*)(d + i) = o;
}

__global__ __launch_bounds__(256)
void cast_w(const float* __restrict__ wq, const float* __restrict__ wk,
            const float* __restrict__ wv, const float* __restrict__ wo,
            bf16_t* __restrict__ d)   // d = [Wq|Wk|Wv|Wo] bf16
{
    size_t t   = (size_t)blockIdx.x * 256 + threadIdx.x;   // 0..524287
    int    sel = (int)(t >> 17);
    const float* s = sel == 0 ? wq : (sel == 1 ? wk : (sel == 2 ? wv : wo));
    size_t off = (t & 131071) * 8;
    float4 a = *(const float4*)(s + off);
    float4 b = *(const float4*)(s + off + 4);
    bfrag o;
    o[0] = (__bf16)a.x; o[1] = (__bf16)a.y; o[2] = (__bf16)a.z; o[3] = (__bf16)a.w;
    o[4] = (__bf16)b.x; o[5] = (__bf16)b.y; o[6] = (__bf16)b.z; o[7] = (__bf16)b.w;
    *(bfrag*)(d + (size_t)sel * 1048576 + off) = o;
}

// ---------------------------------------------------------------------------
// Flash sliding-window attention, transposed frame (S^T / O^T) + block-shared
// K staging (R6 pipeline + R7 frame).
// Block = (b,h, 64-query tile), 4 waves x 16 queries; lane owns ONE query
// (query = lane&15; per-lane scalar softmax state).
//   K: double-buffered LDS, register-prefetched, 1 barrier/iter (R6-proven).
//   S^T = K Q^T  : A = K frags (ds_read_b128), B = Q frags (regs).
//   P^T -> Pw    : 4 packed ds_write_b64 ([query][key], stride 76, 0-conflict).
//   O^T = V^T P^T: A = V^T frags (direct global Vt), B = P^T (ds_read_b128).
// ---------------------------------------------------------------------------
__global__ __launch_bounds__(256, 4)
void attn_win(const bf16_t* __restrict__ QK, const bf16_t* __restrict__ Vt,
              bf16_t* __restrict__ AO)
{
    __shared__ __align__(16) bf16_t Ks[2][64 * 72];     // 18432 B
    __shared__ __align__(16) bf16_t Pw[4][16 * PSTR];   //  9728 B, wave-private

    const int tid  = threadIdx.x;
    const int wid  = tid >> 6;
    const int lane = tid & 63;
    const int n16  = lane & 15;
    const int quad = lane >> 4;

    const int q0 = blockIdx.x * 64;
    const int bh = blockIdx.y;
    const int b  = bh >> 4, h = bh & 15;
    const size_t bS   = (size_t)b * SEQ;
    const size_t hoff = (size_t)h * HD;
    const bf16_t* Vb  = Vt + (size_t)bh * HD * SEQ;   // [d][s]
    const int wstart  = q0 - 512;
    const int it0     = (q0 < 512) ? ((512 - q0) >> 6) : 0;

    // staging map: key-row = tid>>2 (0..63), two 16B chunks per thread
    const int srow  = tid >> 2;
    const int scol0 = (tid & 3) * 16;

    // ---- Q B-frags (once): col n16 = query, k = dims ----
    const int qa = q0 + wid * 16 + n16;               // this lane's query
    bfrag bq0 = *(const bfrag*)(&QK[(bS + qa) * LQK + hoff + quad * 8]);
    bfrag bq1 = *(const bfrag*)(&QK[(bS + qa) * LQK + hoff + 32 + quad * 8]);

    f32x4 ao[4];                                       // O^T: d = j*16+quad*4+r
#pragma unroll
    for (int j = 0; j < 4; j++) ao[j] = (f32x4){0.f, 0.f, 0.f, 0.f};
    float m = -1e30f, l = 0.f;

    // prefetch K for first iteration
    uint4 kp0, kp1;
    {
        const bf16_t* src = &QK[(bS + wstart + it0 * 64 + srow) * LQK + 1024 + hoff + scol0];
        kp0 = *(const uint4*)(src);
        kp1 = *(const uint4*)(src + 8);
    }

    for (int it = it0; it < 9; ++it) {
        const int k0 = wstart + it * 64;
        const int pb = it & 1;
        *(uint4*)(&Ks[pb][srow * 72 + scol0])     = kp0;
        *(uint4*)(&Ks[pb][srow * 72 + scol0 + 8]) = kp1;
        __syncthreads();
        if (it < 8) {
            const bf16_t* src = &QK[(bS + wstart + (it + 1) * 64 + srow) * LQK + 1024 + hoff + scol0];
            kp0 = *(const uint4*)(src);
            kp1 = *(const uint4*)(src + 8);
        }

        // ---- S^T = K Q^T : 4 key-tiles, A = K from LDS ----
        f32x4 a[4];
#pragma unroll
        for (int nt = 0; nt < 4; nt++) {
            bfrag ak0 = *(const bfrag*)(&Ks[pb][(nt * 16 + n16) * 72 + quad * 8]);
            bfrag ak1 = *(const bfrag*)(&Ks[pb][(nt * 16 + n16) * 72 + 32 + quad * 8]);
            f32x4 s4 = (f32x4){0.f, 0.f, 0.f, 0.f};
            s4 = __builtin_amdgcn_mfma_f32_16x16x32_bf16(ak0, bq0, s4, 0, 0, 0);
            s4 = __builtin_amdgcn_mfma_f32_16x16x32_bf16(ak1, bq1, s4, 0, 0, 0);
            a[nt] = s4;
        }

        const bool msk = (it == 0) || (it == 8);
        if (msk) {
#pragma unroll
            for (int nt = 0; nt < 4; nt++)
#pragma unroll
                for (int r = 0; r < 4; r++) {
                    int ka = k0 + nt * 16 + quad * 4 + r;   // S^T row = key
                    bool valid = (ka >= qa - 511) & (ka <= qa);
                    a[nt][r] = valid ? a[nt][r] * 0.125f : -1e30f;
                }
        } else {
#pragma unroll
            for (int nt = 0; nt < 4; nt++)
#pragma unroll
                for (int r = 0; r < 4; r++) a[nt][r] *= 0.125f;
        }

        // ---- online softmax: per-lane scalar state (query = n16) ----
        float cm = -1e30f;
#pragma unroll
        for (int nt = 0; nt < 4; nt++)
#pragma unroll
            for (int r = 0; r < 4; r++) cm = fmaxf(cm, a[nt][r]);
        cm = fmaxf(cm, __shfl_xor(cm, 16, 64));
        cm = fmaxf(cm, __shfl_xor(cm, 32, 64));
        float mn    = fmaxf(m, cm);
        float alpha = __expf(m - mn);
        m = mn;
#pragma unroll
        for (int j = 0; j < 4; j++)
#pragma unroll
            for (int r = 0; r < 4; r++) ao[j][r] *= alpha;

        // ---- p = exp(s-m); packed b64 writes into Pw [query][key] ----
        float lacc = 0.f;
#pragma unroll
        for (int nt = 0; nt < 4; nt++) {
            bf16x4 pk;
#pragma unroll
            for (int r = 0; r < 4; r++) {
                float p = __expf(a[nt][r] - m);
                if (msk && a[nt][r] <= -1e29f) p = 0.f;
                lacc += p;
                pk[r] = (__bf16)p;
            }
            *(bf16x4*)&Pw[wid][n16 * PSTR + nt * 16 + quad * 4] = pk;
        }
        l = l * alpha + lacc;              // cross-quad l-reduce deferred to epilogue

        // ---- O^T += V^T P^T : 2 k-steps of 32 keys ----
#pragma unroll
        for (int ks = 0; ks < 2; ks++) {
            bfrag bp = *(const bfrag*)(&Pw[wid][n16 * PSTR + ks * 32 + quad * 8]);
#pragma unroll
            for (int j = 0; j < 4; j++) {
                bfrag av = *(const bfrag*)(&Vb[(size_t)(j * 16 + n16) * SEQ
                                               + k0 + ks * 32 + quad * 8]);
                ao[j] = __builtin_amdgcn_mfma_f32_16x16x32_bf16(av, bp, ao[j], 0, 0, 0);
            }
        }
    }

    // ---- epilogue: reduce l across quads, store O rows (packed b64) ----
    l += __shfl_xor(l, 16, 64);
    l += __shfl_xor(l, 32, 64);
    const float inv = 1.0f / l;
#pragma unroll
    for (int j = 0; j < 4; j++) {
        bf16x4 pk;
#pragma unroll
        for (int r = 0; r < 4; r++) pk[r] = (__bf16)(ao[j][r] * inv);
        *(bf16x4*)&AO[(bS + qa) * NDIM + hoff + j * 16 + quad * 4] = pk;
    }
}

// ---------------------------------------------------------------------------
extern "C" void kernel_launch(void* const* d_in, const int* in_sizes, int n_in,
                              void* d_out, int out_size, void* d_ws, size_t ws_size,
                              hipStream_t stream)
{
    const float* x  = (const float*)d_in[0];
    const float* Wq = (const float*)d_in[1];
    const float* bq = (const float*)d_in[2];
    const float* Wk = (const float*)d_in[3];
    const float* bk = (const float*)d_in[4];
    const float* Wv = (const float*)d_in[5];
    const float* bv = (const float*)d_in[6];
    const float* Wo = (const float*)d_in[7];
    const float* bo = (const float*)d_in[8];
    float* out = (float*)d_out;

    // ws: QKb [8192][2048] bf16 (32 MiB) | AbX [8192][1024] bf16 (16 MiB)
    //     Wc [Wq|Wk|Wv|Wo] bf16 (8 MiB)
    const size_t QK_E = (size_t)MROWS * LQK;
    const size_t X_E  = (size_t)MROWS * NDIM;
    if (ws_size < (QK_E + X_E + 4u * 1048576u) * sizeof(bf16_t)) return;

    bf16_t* QKb = (bf16_t*)d_ws;
    bf16_t* AbX = QKb + QK_E;
    bf16_t* Wc  = AbX + X_E;
    bf16_t* Wob = Wc + 3u * 1048576u;
    bf16_t* Vtg = (bf16_t*)d_out;   // 16.8 MB scratch inside the 33.5 MB out buf;
                                    // dead before the O-proj overwrites d_out.

    dim3 blk(256);

    cast_x<<<dim3(4096), blk, 0, stream>>>(x, AbX);
    cast_w<<<dim3(2048), blk, 0, stream>>>(Wq, Wk, Wv, Wo, Wc);

    // fused QKV projection: Q,K -> QKb (stride 2048); V -> Vtg transposed
    gemm_bt<bf16_t><<<dim3(3072 / 128, MROWS / 128), blk, 0, stream>>>(
        AbX, NDIM, Wc, bq, bk, bv, QKb, LQK, NDIM, Vtg);

    attn_win<<<dim3(SEQ / 64, NBATCH * NHEAD), blk, 0, stream>>>(QKb, Vtg, AbX);

    // output projection: [8192,1024] x [1024,1024]^T -> fp32 out
    gemm_bt<float><<<dim3(NDIM / 128, MROWS / 128), blk, 0, stream>>>(
        AbX, NDIM, Wob, bo, bo, bo, out, NDIM, NDIM, nullptr);
}